// Round 6
// baseline (329.729 us; speedup 1.0000x reference)
//
#include <hip/hip_runtime.h>
#include <stdint.h>

#define NN 36864        // 192*192 spatial
#define PL 7077888      // 192*NN  per-batch full-C plane
#define PL64 2359296    // 64*NN
#define TOT 14155776    // 2*192*NN elements per output tensor

typedef unsigned short ushort_t;
typedef __attribute__((ext_vector_type(8))) __bf16 bf16x8;
typedef __attribute__((ext_vector_type(4))) float f32x4;
typedef __attribute__((ext_vector_type(4))) unsigned int u32x4;
typedef __attribute__((ext_vector_type(2))) unsigned int u32x2;

__device__ __forceinline__ ushort_t f2bf(float f) {
  unsigned int u = __builtin_bit_cast(unsigned int, f);
  u = (u + 0x7FFFu + ((u >> 16) & 1u)) >> 16;   // RNE
  return (ushort_t)u;
}
__device__ __forceinline__ float bf2f(ushort_t h) {
  unsigned int u = ((unsigned int)h) << 16;
  return __builtin_bit_cast(float, u);
}
__device__ __forceinline__ bf16x8 lds8(const ushort_t* p) {
  return __builtin_bit_cast(bf16x8, *(const u32x4*)p);
}
__device__ __forceinline__ f32x4 mfma16(bf16x8 a, bf16x8 b, f32x4 c) {
  return __builtin_amdgcn_mfma_f32_16x16x32_bf16(a, b, c, 0, 0, 0);
}
__device__ __forceinline__ unsigned cvtpk(float lo, float hi) {
  unsigned r;
  asm("v_cvt_pk_bf16_f32 %0, %1, %2" : "=v"(r) : "v"(lo), "v"(hi));
  return r;
}

// ---------------- weight prep: Wstack = [wq*lnw ; wv] bf16, alpha/beta ----------------
__global__ void k_prep(const float* __restrict__ wq, const float* __restrict__ wv,
                       const float* __restrict__ lnw, const float* __restrict__ lnb,
                       ushort_t* __restrict__ W, float* __restrict__ ab) {
  __shared__ float sa[3], sb[3];
  int r = blockIdx.x, t = threadIdx.x;   // 384 blocks x 192 threads
  if (r < 192) {
    float w  = wq[r*192 + t];
    float lw = lnw[t], lb = lnb[t];
    W[r*192 + t] = f2bf(w * lw);
    float av = w * lb, bv = -w * lw;
    #pragma unroll
    for (int off = 1; off < 64; off <<= 1) {
      av += __shfl_xor(av, off);
      bv += __shfl_xor(bv, off);
    }
    if ((t & 63) == 0) { sa[t >> 6] = av; sb[t >> 6] = bv; }
    __syncthreads();
    if (t == 0) { ab[r] = sa[0]+sa[1]+sa[2]; ab[192 + r] = sb[0]+sb[1]+sb[2]; }
  } else {
    W[r*192 + t] = f2bf(wv[(r-192)*192 + t]);
  }
}

// ---- projection GEMM v4: round-3 proven 128m x 192n dbuf loop + fused LN stats
// ---- + sibling-same-XCD swizzle: bx = g*48 + (mb*2+side)*8 + (bh&7)
__global__ __launch_bounds__(512, 4) void k_proj(
    const float* __restrict__ xl, const float* __restrict__ xr,
    const ushort_t* __restrict__ Wl, const ushort_t* __restrict__ Wr,
    const float* __restrict__ abl, const float* __restrict__ abr,
    ushort_t* __restrict__ qhTl, ushort_t* __restrict__ qhTr,
    ushort_t* __restrict__ qwTl, ushort_t* __restrict__ qwTr,
    ushort_t* __restrict__ Vl, ushort_t* __restrict__ Vr,
    float* __restrict__ gpart) {
  __shared__ union {
    struct { ushort_t A[2][4096]; ushort_t B[2][6144]; } kl;   // 40 KiB dbuf
    struct { ushort_t T[13824]; } ep;                          // q transpose [192][72]
    struct { ushort_t Tv[12800]; } tv;                         // V transpose [64][200]
  } sm;
  __shared__ float spart[4][192], spart2[4][192];              // LN partials
  __shared__ float smu[192], srs[192];
  __shared__ float gsum[64];

  const int bx = blockIdx.x;             // 2304 = 48 groups * (3mb*2side)*8bh
  const int g = bx / 48, rr = bx % 48;
  const int bh = g*8 + (rr & 7);         // b*192 + h
  const int ms = rr >> 3;                // 0..5
  const int mb = ms >> 1, side = ms & 1;
  const int b  = bh / 192, h = bh % 192;
  const int m0 = mb * 128;

  const float*    x  = side ? xr  : xl;
  const ushort_t* W  = side ? Wr  : Wl;
  const float*    ab = side ? abr : abl;
  ushort_t* qhT = side ? qhTr : qhTl;
  ushort_t* qwT = side ? qwTr : qwTl;
  ushort_t* V   = side ? Vr   : Vl;

  const int tid = threadIdx.x;
  const int wave = tid >> 6, lane = tid & 63, lr = lane & 15, lg = lane >> 4;
  const int wm = wave >> 2, wn = wave & 3;

  // B staging mapping (768 tasks: (kg 0..3, n 0..191))
  const int kg0 = tid / 192, n_0 = tid - kg0 * 192;
  const int id1 = 512 + (tid & 255);
  const int kg1 = id1 / 192, n_1 = id1 - kg1 * 192;
  const float* xb0 = x + (size_t)b*PL + (size_t)(kg0*8)*NN + h*192 + n_0;
  const float* xb1 = x + (size_t)b*PL + (size_t)(kg1*8)*NN + h*192 + n_1;
  const int bw0 = n_0*32 + 8*(kg0 ^ ((n_0 >> 1) & 3));
  const int bw1 = n_1*32 + 8*(kg1 ^ ((n_1 >> 1) & 3));
  // A staging: one 16B chunk per thread per step
  const int am = tid >> 2, akb = tid & 3;
  const ushort_t* wsrc = W + (m0 + am)*192 + akb*8;
  const int aw = am*32 + 8*(akb ^ ((am >> 1) & 3));
  const int slotR = 8 * (lg ^ ((lr >> 1) & 3));

  if (tid < 64) gsum[tid] = 0.f;

  const f32x4 fz = {0.f, 0.f, 0.f, 0.f};
  f32x4 acc[4][3];
  #pragma unroll
  for (int mf = 0; mf < 4; ++mf)
    #pragma unroll
    for (int nf = 0; nf < 3; ++nf) acc[mf][nf] = fz;

  float sA0 = 0.f, sB0 = 0.f, sA1 = 0.f, sB1 = 0.f;

  // ---- prologue: stage step 0 into buffer 0 ----
  {
    u32x4 aV = *(const u32x4*)wsrc;
    float g0[8], g1[8];
    #pragma unroll
    for (int j = 0; j < 8; ++j) g0[j] = xb0[(size_t)j*NN];
    if (tid < 256) {
      #pragma unroll
      for (int j = 0; j < 8; ++j) g1[j] = xb1[(size_t)j*NN];
    }
    *(u32x4*)&sm.kl.A[0][aw] = aV;
    union { ushort_t us[8]; u32x4 v; } t0;
    #pragma unroll
    for (int j = 0; j < 8; ++j) { t0.us[j] = f2bf(g0[j]); sA0 += g0[j]; sB0 += g0[j]*g0[j]; }
    *(u32x4*)&sm.kl.B[0][bw0] = t0.v;
    if (tid < 256) {
      union { ushort_t us[8]; u32x4 v; } t1;
      #pragma unroll
      for (int j = 0; j < 8; ++j) { t1.us[j] = f2bf(g1[j]); sA1 += g1[j]; sB1 += g1[j]*g1[j]; }
      *(u32x4*)&sm.kl.B[0][bw1] = t1.v;
    }
  }
  __syncthreads();

  // ---- main K loop (T14: issue next loads early, ds_write after compute) ----
  for (int ks = 0; ks < 6; ++ks) {
    const int cur = ks & 1, nxt = cur ^ 1;
    u32x4 aN;
    float g0[8], g1[8];
    if (ks < 5) {
      const int k0n = (ks + 1) * 32;
      aN = *(const u32x4*)(wsrc + k0n);
      #pragma unroll
      for (int j = 0; j < 8; ++j) g0[j] = xb0[(size_t)(k0n + j)*NN];
      if (tid < 256) {
        #pragma unroll
        for (int j = 0; j < 8; ++j) g1[j] = xb1[(size_t)(k0n + j)*NN];
      }
    }
    bf16x8 bfr[3];
    #pragma unroll
    for (int nf = 0; nf < 3; ++nf)
      bfr[nf] = lds8(&sm.kl.B[cur][(wn*48 + nf*16 + lr)*32 + slotR]);
    #pragma unroll
    for (int mf = 0; mf < 4; ++mf) {
      bf16x8 af = lds8(&sm.kl.A[cur][(wm*64 + mf*16 + lr)*32 + slotR]);
      #pragma unroll
      for (int nf = 0; nf < 3; ++nf) acc[mf][nf] = mfma16(af, bfr[nf], acc[mf][nf]);
    }
    if (ks < 5) {
      *(u32x4*)&sm.kl.A[nxt][aw] = aN;
      union { ushort_t us[8]; u32x4 v; } t0;
      #pragma unroll
      for (int j = 0; j < 8; ++j) { t0.us[j] = f2bf(g0[j]); sA0 += g0[j]; sB0 += g0[j]*g0[j]; }
      *(u32x4*)&sm.kl.B[nxt][bw0] = t0.v;
      if (tid < 256) {
        union { ushort_t us[8]; u32x4 v; } t1;
        #pragma unroll
        for (int j = 0; j < 8; ++j) { t1.us[j] = f2bf(g1[j]); sA1 += g1[j]; sB1 += g1[j]*g1[j]; }
        *(u32x4*)&sm.kl.B[nxt][bw1] = t1.v;
      }
    }
    __syncthreads();
  }

  // ---- fused LN stats (deterministic tree; full K staged by every sibling) ----
  spart[kg0][n_0] = sA0; spart2[kg0][n_0] = sB0;
  if (tid < 256) { spart[kg1][n_1] = sA1; spart2[kg1][n_1] = sB1; }
  __syncthreads();
  if (tid < 192) {
    float s  = spart[0][tid] + spart[1][tid] + spart[2][tid] + spart[3][tid];
    float s2 = spart2[0][tid] + spart2[1][tid] + spart2[2][tid] + spart2[3][tid];
    float mu = s * (1.f/192.f);
    float var = s2 * (1.f/192.f) - mu*mu;
    smu[tid] = mu;
    srs[tid] = rsqrtf(var + 1e-6f);
  }
  __syncthreads();

  if (mb == 0) {
    // ---- q rows 0..127: LN fixup ----
    float rst[3], mrs[3];
    #pragma unroll
    for (int nf = 0; nf < 3; ++nf) {
      int n_ = wn*48 + nf*16 + lr;
      float rs = srs[n_];
      rst[nf] = rs;
      mrs[nf] = smu[n_] * rs;
    }
    #pragma unroll
    for (int mf = 0; mf < 4; ++mf) {
      #pragma unroll
      for (int i = 0; i < 4; ++i) {
        int m = wm*64 + mf*16 + lg*4 + i;
        float a_ = ab[m], bb = ab[192 + m];
        #pragma unroll
        for (int nf = 0; nf < 3; ++nf)
          acc[mf][nf][i] = acc[mf][nf][i]*rst[nf] + bb*mrs[nf] + a_;
      }
    }
    // phase A: q_h (c 0..63, wm==0) -> qhT [b][w][h][c]
    if (wm == 0) {
      #pragma unroll
      for (int mf = 0; mf < 4; ++mf)
        #pragma unroll
        for (int nf = 0; nf < 3; ++nf)
          #pragma unroll
          for (int i = 0; i < 4; ++i)
            sm.ep.T[(wn*48 + nf*16 + lr)*72 + mf*16 + lg*4 + i] = f2bf(acc[mf][nf][i]);
    }
    __syncthreads();
    #pragma unroll
    for (int p = 0; p < 3; ++p) {
      int id = p*512 + tid, n = id >> 3, c8 = id & 7;
      u32x4 v = *(const u32x4*)&sm.ep.T[n*72 + c8*8];
      *(u32x4*)&qhT[(((size_t)b*192 + n)*192 + h)*64 + c8*8] = v;
    }
    __syncthreads();
    // phase B: q_w (c 0..63 of q_w = rows 64..127, wm==1) -> qwT [b][h][w][c]
    if (wm == 1) {
      #pragma unroll
      for (int mf = 0; mf < 4; ++mf)
        #pragma unroll
        for (int nf = 0; nf < 3; ++nf)
          #pragma unroll
          for (int i = 0; i < 4; ++i)
            sm.ep.T[(wn*48 + nf*16 + lr)*72 + mf*16 + lg*4 + i] = f2bf(acc[mf][nf][i]);
    }
    __syncthreads();
    #pragma unroll
    for (int p = 0; p < 3; ++p) {
      int id = p*512 + tid, n = id >> 3, c8 = id & 7;
      u32x4 v = *(const u32x4*)&sm.ep.T[n*72 + c8*8];
      *(u32x4*)&qwT[(((size_t)b*192 + h)*192 + n)*64 + c8*8] = v;
    }
  } else if (mb == 1) {
    // ---- rows 128..191 (wm==0): q_c fixup + GAP; rows 192..255 (wm==1): V c 0..63 ----
    if (wm == 0) {
      float rst[3], mrs[3];
      #pragma unroll
      for (int nf = 0; nf < 3; ++nf) {
        int n_ = wn*48 + nf*16 + lr;
        float rs = srs[n_];
        rst[nf] = rs;
        mrs[nf] = smu[n_] * rs;
      }
      #pragma unroll
      for (int mf = 0; mf < 4; ++mf) {
        #pragma unroll
        for (int i = 0; i < 4; ++i) {
          int m = 128 + mf*16 + lg*4 + i;
          float a_ = ab[m], bb = ab[192 + m];
          float part = 0.f;
          #pragma unroll
          for (int nf = 0; nf < 3; ++nf)
            part += acc[mf][nf][i]*rst[nf] + bb*mrs[nf] + a_;
          #pragma unroll
          for (int off = 1; off < 16; off <<= 1) part += __shfl_xor(part, off);
          if (lr == 0) atomicAdd(&gsum[mf*16 + lg*4 + i], part);
        }
      }
    } else {
      // V c 0..63 -> Tv transpose
      #pragma unroll
      for (int mf = 0; mf < 4; ++mf)
        #pragma unroll
        for (int nf = 0; nf < 3; ++nf)
          #pragma unroll
          for (int i = 0; i < 4; ++i)
            sm.tv.Tv[(mf*16 + lg*4 + i)*200 + wn*48 + nf*16 + lr] = f2bf(acc[mf][nf][i]);
    }
    __syncthreads();
    if (tid < 64) gpart[(((size_t)side*2 + b)*192 + h)*64 + tid] = gsum[tid];
    #pragma unroll
    for (int p = 0; p < 3; ++p) {
      int id = p*512 + tid;
      int cc = id / 24, seg = id % 24;
      u32x4 v = *(const u32x4*)&sm.tv.Tv[cc*200 + seg*8];
      *(u32x4*)&V[((size_t)b*192 + cc)*NN + h*192 + seg*8] = v;
    }
  } else {
    // ---- mb==2: rows 256..383 -> V c 64..191, two transpose passes ----
    #pragma unroll
    for (int ch = 0; ch < 2; ++ch) {
      if (wm == ch) {
        #pragma unroll
        for (int mf = 0; mf < 4; ++mf)
          #pragma unroll
          for (int nf = 0; nf < 3; ++nf)
            #pragma unroll
            for (int i = 0; i < 4; ++i)
              sm.tv.Tv[(mf*16 + lg*4 + i)*200 + wn*48 + nf*16 + lr] = f2bf(acc[mf][nf][i]);
      }
      __syncthreads();
      #pragma unroll
      for (int p = 0; p < 3; ++p) {
        int id = p*512 + tid;
        int cc = id / 24, seg = id % 24;
        u32x4 v = *(const u32x4*)&sm.tv.Tv[cc*200 + seg*8];
        *(u32x4*)&V[((size_t)b*192 + 64 + ch*64 + cc)*NN + h*192 + seg*8] = v;
      }
      __syncthreads();
    }
  }
}

// ---------------- repack v_h (ch 0..63 of V): [b][c][h][w] -> [b][c][w][h] ----------------
__global__ void k_repack_v(const ushort_t* __restrict__ Vl, const ushort_t* __restrict__ Vr,
                           ushort_t* __restrict__ vhTl, ushort_t* __restrict__ vhTr) {
  __shared__ ushort_t Ls[64*72];
  const ushort_t* V = blockIdx.y ? Vr : Vl;
  ushort_t* out = blockIdx.y ? vhTr : vhTl;
  int bx = blockIdx.x;                    // 1152 = 2b * 64c * 9 tiles
  int b = bx / 576, rem = bx % 576;
  int c = rem / 9, tt = rem % 9;
  int h0 = (tt/3)*64, w0 = (tt%3)*64;
  int tid = threadIdx.x;
  #pragma unroll
  for (int i = 0; i < 2; ++i) {
    int idx = tid + 256*i;
    int hh = idx >> 3, wb = idx & 7;
    *(u32x4*)&Ls[hh*72 + wb*8] =
      *(const u32x4*)&V[(size_t)(b*192 + c)*NN + (h0+hh)*192 + w0 + wb*8];
  }
  __syncthreads();
  #pragma unroll
  for (int i = 0; i < 2; ++i) {
    int idx = tid + 256*i;
    int ww = idx >> 3, hb = idx & 7;
    union { ushort_t us[8]; u32x4 v; } tu;
    #pragma unroll
    for (int j = 0; j < 8; ++j) tu.us[j] = Ls[(hb*8+j)*72 + ww];
    *(u32x4*)&out[(size_t)(b*64 + c)*NN + (w0+ww)*192 + h0 + hb*8] = tu.v;
  }
}

// ------- fused axial attention; O written [b][s0][col][c64] via LDS transpose -------
__global__ __launch_bounds__(256, 2) void k_attn(
    const ushort_t* __restrict__ qhTl, const ushort_t* __restrict__ qhTr,
    const ushort_t* __restrict__ qwTl, const ushort_t* __restrict__ qwTr,
    const ushort_t* __restrict__ Vl,  const ushort_t* __restrict__ Vr,
    const ushort_t* __restrict__ vhTl, const ushort_t* __restrict__ vhTr,
    const float* __restrict__ sch, const float* __restrict__ scw,
    ushort_t* __restrict__ Oh1, ushort_t* __restrict__ Oh2,
    ushort_t* __restrict__ Ow1, ushort_t* __restrict__ Ow2) {
  __shared__ ushort_t Qsl[192*64];   // swizzled [row][slot^row&7]; reused as O-transpose buf
  __shared__ ushort_t Qsr[192*64];
  __shared__ ushort_t Vs[64*192];    // swizzled [c][slot^c&7]
  __shared__ float md[192*2];        // per-col (max, 1/den) from pass1

  const int tid = threadIdx.x;
  const int wave = tid >> 6, lane = tid & 63, lr = lane & 15, lg = lane >> 4;
  const int bx = blockIdx.x;
  const int mode = bx / 384;
  const int b = (bx % 384) / 192, s0 = bx % 192;
  const float scl = (mode ? scw : sch)[0];

  const ushort_t* ql = (mode ? qwTl : qhTl) + (size_t)(b*192 + s0)*12288;
  const ushort_t* qr = (mode ? qwTr : qhTr) + (size_t)(b*192 + s0)*12288;
  const ushort_t* vr = mode ? Vr + (size_t)(b*192 + 64)*NN + s0*192
                            : vhTr + (size_t)b*PL64 + s0*192;
  const ushort_t* vl = mode ? Vl + (size_t)(b*192 + 64)*NN + s0*192
                            : vhTl + (size_t)b*PL64 + s0*192;
  ushort_t* og1 = (mode ? Ow1 : Oh1) + (size_t)(b*192 + s0)*12288;
  ushort_t* og2 = (mode ? Ow2 : Oh2) + (size_t)(b*192 + s0)*12288;

  // ---- stage Q_l, Q_r, V_r (swizzled) ----
  #pragma unroll
  for (int i = 0; i < 6; ++i) {
    int idx = tid + 256*i;
    int r = idx >> 3, sl = idx & 7;
    int dq = r*64 + ((sl ^ (r & 7)) << 3);
    *(u32x4*)&Qsl[dq] = *(const u32x4*)&ql[idx*8];
    *(u32x4*)&Qsr[dq] = *(const u32x4*)&qr[idx*8];
    int c = idx / 24, gs = idx % 24;
    *(u32x4*)&Vs[c*192 + ((gs ^ (c & 7)) << 3)] = *(const u32x4*)&vr[(size_t)c*NN + gs*8];
  }
  __syncthreads();

  const f32x4 fz = {0.f, 0.f, 0.f, 0.f};
  f32x4 acc[12][3];
  unsigned pk[3][12][2];

  auto qk = [&](bool swap) {
    const ushort_t* A  = swap ? Qsl : Qsr;
    const ushort_t* Bq = swap ? Qsr : Qsl;
    #pragma unroll
    for (int mf = 0; mf < 12; ++mf)
      #pragma unroll
      for (int nf = 0; nf < 3; ++nf) acc[mf][nf] = fz;
    __builtin_amdgcn_s_setprio(1);
    #pragma unroll
    for (int kh = 0; kh < 2; ++kh) {
      bf16x8 bq[3];
      #pragma unroll
      for (int nf = 0; nf < 3; ++nf) {
        int r = wave*48 + nf*16 + lr;
        bq[nf] = lds8(&Bq[r*64 + (((kh*4 + lg) ^ (r & 7)) << 3)]);
      }
      #pragma unroll
      for (int mf = 0; mf < 12; ++mf) {
        int r = mf*16 + lr;
        bf16x8 aq = lds8(&A[r*64 + (((kh*4 + lg) ^ (r & 7)) << 3)]);
        #pragma unroll
        for (int nf = 0; nf < 3; ++nf) acc[mf][nf] = mfma16(aq, bq[nf], acc[mf][nf]);
      }
    }
    __builtin_amdgcn_s_setprio(0);
  };

  auto smpack = [&](bool store_md) {
    #pragma unroll
    for (int nf = 0; nf < 3; ++nf) {
      float mx = -3.4e38f;
      #pragma unroll
      for (int mf = 0; mf < 12; ++mf)
        #pragma unroll
        for (int i = 0; i < 4; ++i) {
          float v = acc[mf][nf][i] * scl;
          acc[mf][nf][i] = v;
          mx = fmaxf(mx, v);
        }
      mx = fmaxf(mx, __shfl_xor(mx, 16));
      mx = fmaxf(mx, __shfl_xor(mx, 32));
      float den = 0.f;
      #pragma unroll
      for (int mf = 0; mf < 12; ++mf)
        #pragma unroll
        for (int i = 0; i < 4; ++i) {
          float e = __expf(acc[mf][nf][i] - mx);
          acc[mf][nf][i] = e;
          den += e;
        }
      den += __shfl_xor(den, 16);
      den += __shfl_xor(den, 32);
      float rd = 1.f / den;
      if (store_md && lg == 0) {
        int col = wave*48 + nf*16 + lr;
        md[col*2] = mx; md[col*2+1] = rd;
      }
      #pragma unroll
      for (int mf = 0; mf < 12; ++mf) {
        pk[nf][mf][0] = cvtpk(acc[mf][nf][0]*rd, acc[mf][nf][1]*rd);
        pk[nf][mf][1] = cvtpk(acc[mf][nf][2]*rd, acc[mf][nf][3]*rd);
      }
    }
  };

  // PV -> bf16 fragment pairs (obf[mf][nf] = packed c=(mf*16+lg*4)+0..3 at col)
  auto pv = [&](unsigned obf[4][3][2]) {
    f32x4 o[4][3];
    #pragma unroll
    for (int mf = 0; mf < 4; ++mf)
      #pragma unroll
      for (int nf = 0; nf < 3; ++nf) o[mf][nf] = fz;
    const int sA = lr + 32*(lg & 1), sB = sA + 16;
    const bool hi = (lg >> 1) != 0;
    __builtin_amdgcn_s_setprio(1);
    #pragma unroll
    for (int ks = 0; ks < 6; ++ks) {
      bf16x8 av[4];
      #pragma unroll
      for (int mf = 0; mf < 4; ++mf) {
        int c = mf*16 + lr;
        av[mf] = lds8(&Vs[c*192 + (((4*ks + lg) ^ (c & 7)) << 3)]);
      }
      #pragma unroll
      for (int nf = 0; nf < 3; ++nf) {
        unsigned w0a = (unsigned)__shfl((int)pk[nf][2*ks  ][0], sA);
        unsigned w0b = (unsigned)__shfl((int)pk[nf][2*ks+1][0], sA);
        unsigned w1a = (unsigned)__shfl((int)pk[nf][2*ks  ][1], sA);
        unsigned w1b = (unsigned)__shfl((int)pk[nf][2*ks+1][1], sA);
        unsigned w2a = (unsigned)__shfl((int)pk[nf][2*ks  ][0], sB);
        unsigned w2b = (unsigned)__shfl((int)pk[nf][2*ks+1][0], sB);
        unsigned w3a = (unsigned)__shfl((int)pk[nf][2*ks  ][1], sB);
        unsigned w3b = (unsigned)__shfl((int)pk[nf][2*ks+1][1], sB);
        u32x4 wv = { hi ? w0b : w0a, hi ? w1b : w1a, hi ? w2b : w2a, hi ? w3b : w3a };
        bf16x8 bp = __builtin_bit_cast(bf16x8, wv);
        #pragma unroll
        for (int mf = 0; mf < 4; ++mf) o[mf][nf] = mfma16(av[mf], bp, o[mf][nf]);
      }
    }
    __builtin_amdgcn_s_setprio(0);
    #pragma unroll
    for (int mf = 0; mf < 4; ++mf)
      #pragma unroll
      for (int nf = 0; nf < 3; ++nf) {
        obf[mf][nf][0] = cvtpk(o[mf][nf][0], o[mf][nf][1]);
        obf[mf][nf][1] = cvtpk(o[mf][nf][2], o[mf][nf][3]);
      }
  };

  // write packed O frags into Qsl region as [col(192)][c(64)] with XOR swizzle
  auto owrite = [&](unsigned obf[4][3][2]) {
    char* Ot = (char*)Qsl;
    #pragma unroll
    for (int mf = 0; mf < 4; ++mf)
      #pragma unroll
      for (int nf = 0; nf < 3; ++nf) {
        int col = wave*48 + nf*16 + lr;
        int byte = col*128 + ((mf*32 + lg*8) ^ ((col & 7) << 4));
        u32x2 v = { obf[mf][nf][0], obf[mf][nf][1] };
        *(u32x2*)(Ot + byte) = v;
      }
  };

  // coalesced store: [s0][col][c] contiguous 24KB slab
  auto ostore = [&](ushort_t* og) {
    const char* Ot = (const char*)Qsl;
    #pragma unroll
    for (int it = 0; it < 6; ++it) {
      int id = tid + 256*it;
      int col = id >> 3, s = id & 7;
      int byte = col*128 + ((s*16) ^ ((col & 7) << 4));
      u32x4 v = *(const u32x4*)(Ot + byte);
      *(u32x4*)&og[(size_t)col*64 + s*8] = v;
    }
  };

  // ---- pass 1 ----
  qk(false);
  smpack(true);
  unsigned o1bf[4][3][2];
  pv(o1bf);

  u32x4 vlr[6];                           // prefetch V_l (T14)
  #pragma unroll
  for (int i = 0; i < 6; ++i) {
    int idx = tid + 256*i;
    int c = idx / 24, gs = idx % 24;
    vlr[i] = *(const u32x4*)&vl[(size_t)c*NN + gs*8];
  }

  // ---- pass 2 QK (Q still resident) ----
  qk(true);
  __syncthreads();                        // all Q/Vs reads + md writes done

  owrite(o1bf);                           // O1 -> Qsl region
  #pragma unroll
  for (int i = 0; i < 6; ++i) {           // V_l -> Vs
    int idx = tid + 256*i;
    int c = idx / 24, gs = idx % 24;
    *(u32x4*)&Vs[c*192 + ((gs ^ (c & 7)) << 3)] = vlr[i];
  }

  if (mode == 0) {                        // H: reuse pass1 stats keyed by row h
    #pragma unroll
    for (int mf = 0; mf < 12; ++mf)
      #pragma unroll
      for (int i = 0; i < 4; ++i) {
        int row = mf*16 + lg*4 + i;
        float m_ = md[row*2], rd_ = md[row*2+1];
        #pragma unroll
        for (int nf = 0; nf < 3; ++nf)
          acc[mf][nf][i] = __expf(acc[mf][nf][i]*scl - m_) * rd_;
      }
    #pragma unroll
    for (int nf = 0; nf < 3; ++nf)
      #pragma unroll
      for (int mf = 0; mf < 12; ++mf) {
        pk[nf][mf][0] = cvtpk(acc[mf][nf][0], acc[mf][nf][1]);
        pk[nf][mf][1] = cvtpk(acc[mf][nf][2], acc[mf][nf][3]);
      }
  } else {
    smpack(false);
  }
  __syncthreads();                        // O1 LDS + V_l staged

  ostore(og1);
  unsigned o2bf[4][3][2];
  pv(o2bf);
  __syncthreads();                        // O1 LDS reads done
  owrite(o2bf);
  __syncthreads();
  ostore(og2);
}

// ---------------- SE: reduce gpart + MLP ----------------
__global__ void k_se(const float* __restrict__ gpart, const float* __restrict__ w1,
                     const float* __restrict__ w2, float* __restrict__ sea) {
  __shared__ float p[2][64];
  __shared__ float h1[2][8];
  __shared__ float lgt[2][128];
  __shared__ float mred[2], dred[2];
  int t = threadIdx.x;
  if (t < 128) {
    int b = t >> 6, c = t & 63;
    float s = 0.f;
    for (int side = 0; side < 2; ++side)
      for (int h = 0; h < 192; ++h)
        s += gpart[(((size_t)side*2 + b)*192 + h)*64 + c];
    p[b][c] = s * (1.f/36864.f);
  }
  __syncthreads();
  if (t < 16) {
    int bb = t >> 3, j = t & 7;
    float s = 0.f;
    for (int k = 0; k < 64; ++k) s += p[bb][k] * w1[j*64 + k];
    h1[bb][j] = fmaxf(s, 0.f);
  }
  __syncthreads();
  {
    int bb = t >> 7, o = t & 127;
    float s = 0.f;
    #pragma unroll
    for (int j = 0; j < 8; ++j) s += h1[bb][j] * w2[o*8 + j];
    lgt[bb][o] = s;
  }
  __syncthreads();
  if (t < 2) {
    float mx = -3.4e38f;
    for (int o = 0; o < 128; ++o) mx = fmaxf(mx, lgt[t][o]);
    float d = 0.f;
    for (int o = 0; o < 128; ++o) d += __expf(lgt[t][o] - mx);
    mred[t] = mx; dred[t] = d;
  }
  __syncthreads();
  {
    int bb = t >> 7, o = t & 127;
    sea[bb*128 + o] = __expf(lgt[bb][o] - mred[bb]) / dred[bb];
  }
}

// --------- unified epilogue: block (dir,b,h); O layouts [sp1][sp2][c] ---------
__global__ __launch_bounds__(256, 4) void k_ep(
    const ushort_t* __restrict__ Oh1, const ushort_t* __restrict__ Oh2,
    const ushort_t* __restrict__ Ow1, const ushort_t* __restrict__ Ow2,
    const ushort_t* __restrict__ Vl, const ushort_t* __restrict__ Vr,
    const float* __restrict__ sea,
    const float* __restrict__ xl, const float* __restrict__ xr,
    const float* __restrict__ ls1, const float* __restrict__ ls2,
    float* __restrict__ out) {
  __shared__ ushort_t T[192*64];          // 24KB swizzled [w][c]
  const int gid = blockIdx.x;             // 768 = 2dir*2b*192h
  const int h = gid % 192;
  const int b = (gid / 192) % 2;
  const int dir = gid / 384;
  const int tid = threadIdx.x;
  const float* xin = dir ? xr : xl;
  const float* ls  = dir ? ls2 : ls1;
  const ushort_t* Oh = dir ? Oh2 : Oh1;
  const ushort_t* Ow = dir ? Ow2 : Ow1;
  const ushort_t* Vv = dir ? Vr  : Vl;
  float* outp = out + (size_t)dir*TOT;

  const int c0 = (tid / 24) * 8, wseg = tid % 24, w0 = wseg * 8;
  const int Srd = (wseg & 7) << 4;

  // transpose T -> out channels [cbase + c0 .. +7]
  auto flush = [&](int cbase) {
    if (tid < 192) {
      u32x4 r[8];
      #pragma unroll
      for (int j = 0; j < 8; ++j)
        r[j] = *(const u32x4*)((const char*)T + (w0 + j)*128 + ((c0*2) ^ Srd));
      #pragma unroll
      for (int k = 0; k < 8; ++k) {
        int c = cbase + c0 + k;
        float lsv = ls[c];
        size_t oo = (size_t)(b*192 + c)*NN + h*192 + w0;
        f32x4 xa = *(const f32x4*)&xin[oo];
        f32x4 xb2 = *(const f32x4*)&xin[oo + 4];
        f32x4 r0, r1;
        #pragma unroll
        for (int j = 0; j < 4; ++j) r0[j] = bf2f(((const ushort_t*)&r[j])[k])*lsv + xa[j];
        #pragma unroll
        for (int j = 0; j < 4; ++j) r1[j] = bf2f(((const ushort_t*)&r[4+j])[k])*lsv + xb2[j];
        *(f32x4*)&outp[oo] = r0;
        *(f32x4*)&outp[oo + 4] = r1;
      }
    }
  };

  // Phase A: c 0..63 from Oh[b][w][h][c]
  {
    const ushort_t* ohb = Oh + ((size_t)b*192*192 + h)*64;
    #pragma unroll
    for (int it = 0; it < 6; ++it) {
      int id = tid + 256*it;
      int w = id >> 3, s = id & 7;
      u32x4 v = *(const u32x4*)&ohb[(size_t)w*12288 + s*8];
      *(u32x4*)((char*)T + w*128 + ((s*16) ^ (((w >> 3) & 7) << 4))) = v;
    }
  }
  __syncthreads();
  flush(0);
  __syncthreads();

  // Phase B: c 64..127 from Ow[b][h][w][c] (contiguous slab)
  {
    const ushort_t* owb = Ow + ((size_t)b*192 + h)*12288;
    #pragma unroll
    for (int it = 0; it < 6; ++it) {
      int id = tid + 256*it;
      int w = id >> 3, s = id & 7;
      u32x4 v = *(const u32x4*)&owb[id*8];
      *(u32x4*)((char*)T + w*128 + ((s*16) ^ (((w >> 3) & 7) << 4))) = v;
    }
  }
  __syncthreads();
  flush(64);

  // Phase C: c 128..191 elementwise SE from V
  #pragma unroll
  for (int it = 0; it < 6; ++it) {
    int id = tid + 256*it;
    int cc = id / 24, ws = (id % 24) * 8;
    float lsv = ls[128 + cc] * sea[b*128 + dir*64 + cc];
    size_t oo = (size_t)(b*192 + 128 + cc)*NN + h*192 + ws;
    u32x4 sv = *(const u32x4*)&Vv[(size_t)(b*192 + 128 + cc)*NN + h*192 + ws];
    const ushort_t* sp = (const ushort_t*)&sv;
    f32x4 xa = *(const f32x4*)&xin[oo];
    f32x4 xb2 = *(const f32x4*)&xin[oo + 4];
    f32x4 r0, r1;
    #pragma unroll
    for (int j = 0; j < 4; ++j) r0[j] = bf2f(sp[j])*lsv + xa[j];
    #pragma unroll
    for (int j = 0; j < 4; ++j) r1[j] = bf2f(sp[4+j])*lsv + xb2[j];
    *(f32x4*)&outp[oo] = r0;
    *(f32x4*)&outp[oo + 4] = r1;
  }
}

extern "C" void kernel_launch(void* const* d_in, const int* in_sizes, int n_in,
                              void* d_out, int out_size, void* d_ws, size_t ws_size,
                              hipStream_t stream) {
  const float* x_l  = (const float*)d_in[0];
  const float* x_r  = (const float*)d_in[1];
  const float* lnlw = (const float*)d_in[2];
  const float* lnlb = (const float*)d_in[3];
  const float* lnrw = (const float*)d_in[4];
  const float* lnrb = (const float*)d_in[5];
  const float* wq_l = (const float*)d_in[6];
  const float* wq_r = (const float*)d_in[7];
  const float* wv_l = (const float*)d_in[8];
  const float* wv_r = (const float*)d_in[9];
  const float* w1   = (const float*)d_in[10];
  const float* w2   = (const float*)d_in[11];
  const float* sch  = (const float*)d_in[12];
  const float* scw  = (const float*)d_in[13];
  const float* ls1  = (const float*)d_in[14];
  const float* ls2  = (const float*)d_in[15];
  float* out = (float*)d_out;

  char* ws = (char*)d_ws;
  size_t off = 0;
  auto alloc = [&](size_t bytes) {
    char* p = ws + off;
    off += (bytes + 255) & ~(size_t)255;
    return p;
  };
  ushort_t* Vl   = (ushort_t*)alloc((size_t)2*192*NN*2);
  ushort_t* Vr   = (ushort_t*)alloc((size_t)2*192*NN*2);
  ushort_t* qhTl = (ushort_t*)alloc((size_t)2*64*NN*2);
  ushort_t* qhTr = (ushort_t*)alloc((size_t)2*64*NN*2);
  ushort_t* qwTl = (ushort_t*)alloc((size_t)2*64*NN*2);
  ushort_t* qwTr = (ushort_t*)alloc((size_t)2*64*NN*2);
  ushort_t* vhTl = (ushort_t*)alloc((size_t)2*64*NN*2);
  ushort_t* vhTr = (ushort_t*)alloc((size_t)2*64*NN*2);
  ushort_t* Oh1  = (ushort_t*)alloc((size_t)2*64*NN*2);
  ushort_t* Oh2  = (ushort_t*)alloc((size_t)2*64*NN*2);
  ushort_t* Ow1  = (ushort_t*)alloc((size_t)2*64*NN*2);
  ushort_t* Ow2  = (ushort_t*)alloc((size_t)2*64*NN*2);
  ushort_t* Wl   = (ushort_t*)alloc((size_t)384*192*2);
  ushort_t* Wr   = (ushort_t*)alloc((size_t)384*192*2);
  float* abl = (float*)alloc(384*4);
  float* abr = (float*)alloc(384*4);
  float* gpart = (float*)alloc((size_t)2*2*192*64*4);
  float* sea = (float*)alloc(2*128*4);
  (void)in_sizes; (void)n_in; (void)out_size; (void)ws_size;

  k_prep<<<384, 192, 0, stream>>>(wq_l, wv_l, lnlw, lnlb, Wl, abl);
  k_prep<<<384, 192, 0, stream>>>(wq_r, wv_r, lnrw, lnrb, Wr, abr);
  k_proj<<<2304, 512, 0, stream>>>(x_l, x_r, Wl, Wr, abl, abr,
                                   qhTl, qhTr, qwTl, qwTr, Vl, Vr, gpart);
  k_repack_v<<<dim3(1152, 2), 256, 0, stream>>>(Vl, Vr, vhTl, vhTr);
  k_attn<<<768, 256, 0, stream>>>(qhTl, qhTr, qwTl, qwTr, Vl, Vr, vhTl, vhTr,
                                  sch, scw, Oh1, Oh2, Ow1, Ow2);
  k_se<<<1, 256, 0, stream>>>(gpart, w1, w2, sea);
  k_ep<<<768, 256, 0, stream>>>(Oh1, Oh2, Ow1, Ow2, Vl, Vr, sea,
                                x_l, x_r, ls1, ls2, out);
}

// Round 7
// 232.838 us; speedup vs baseline: 1.4161x; 1.4161x over previous
//
#include <hip/hip_runtime.h>
#include <stdint.h>

#define NN 36864        // 192*192 spatial
#define PL 7077888      // 192*NN  per-batch full-C plane
#define PL64 2359296    // 64*NN
#define TOT 14155776    // 2*192*NN elements per output tensor

typedef unsigned short ushort_t;
typedef __attribute__((ext_vector_type(8))) __bf16 bf16x8;
typedef __attribute__((ext_vector_type(4))) float f32x4;
typedef __attribute__((ext_vector_type(4))) unsigned int u32x4;
typedef __attribute__((ext_vector_type(2))) unsigned int u32x2;

__device__ __forceinline__ ushort_t f2bf(float f) {
  unsigned int u = __builtin_bit_cast(unsigned int, f);
  u = (u + 0x7FFFu + ((u >> 16) & 1u)) >> 16;   // RNE
  return (ushort_t)u;
}
__device__ __forceinline__ float bf2f(ushort_t h) {
  unsigned int u = ((unsigned int)h) << 16;
  return __builtin_bit_cast(float, u);
}
__device__ __forceinline__ bf16x8 lds8(const ushort_t* p) {
  return __builtin_bit_cast(bf16x8, *(const u32x4*)p);
}
__device__ __forceinline__ f32x4 mfma16(bf16x8 a, bf16x8 b, f32x4 c) {
  return __builtin_amdgcn_mfma_f32_16x16x32_bf16(a, b, c, 0, 0, 0);
}
__device__ __forceinline__ unsigned cvtpk(float lo, float hi) {
  unsigned r;
  asm("v_cvt_pk_bf16_f32 %0, %1, %2" : "=v"(r) : "v"(lo), "v"(hi));
  return r;
}

// ---------------- weight prep: Wstack = [wq*lnw ; wv] bf16, alpha/beta ----------------
__global__ void k_prep(const float* __restrict__ wq, const float* __restrict__ wv,
                       const float* __restrict__ lnw, const float* __restrict__ lnb,
                       ushort_t* __restrict__ W, float* __restrict__ ab) {
  __shared__ float sa[3], sb[3];
  int r = blockIdx.x, t = threadIdx.x;   // 384 blocks x 192 threads
  if (r < 192) {
    float w  = wq[r*192 + t];
    float lw = lnw[t], lb = lnb[t];
    W[r*192 + t] = f2bf(w * lw);
    float av = w * lb, bv = -w * lw;
    #pragma unroll
    for (int off = 1; off < 64; off <<= 1) {
      av += __shfl_xor(av, off);
      bv += __shfl_xor(bv, off);
    }
    if ((t & 63) == 0) { sa[t >> 6] = av; sb[t >> 6] = bv; }
    __syncthreads();
    if (t == 0) { ab[r] = sa[0]+sa[1]+sa[2]; ab[192 + r] = sb[0]+sb[1]+sb[2]; }
  } else {
    W[r*192 + t] = f2bf(wv[(r-192)*192 + t]);
  }
}

// ---- projection GEMM v5: N-split. Block = (b,h,ws,side): C[384,64] = W @ x[192,64].
// ---- x disjoint per block (read once). B staged fully up-front; K-loop barrier-free.
__global__ __launch_bounds__(512, 4) void k_proj(
    const float* __restrict__ xl, const float* __restrict__ xr,
    const ushort_t* __restrict__ Wl, const ushort_t* __restrict__ Wr,
    const float* __restrict__ abl, const float* __restrict__ abr,
    ushort_t* __restrict__ qhTl, ushort_t* __restrict__ qhTr,
    ushort_t* __restrict__ qwTl, ushort_t* __restrict__ qwTr,
    ushort_t* __restrict__ Vl, ushort_t* __restrict__ Vr,
    float* __restrict__ gpart) {
  __shared__ union {
    ushort_t B[64*192];        // 24 KiB: [n 64][k 192] rows 384B, 16B slots swizzled
    ushort_t T[64*72];         // 9 KiB transpose buf [col 64][c 64 pad 72]
  } sm;
  __shared__ float spart[8][64], spart2[8][64];   // 4 KiB LN partials
  __shared__ float smu[64], srs[64];
  __shared__ float gsum[64];

  const int bx = blockIdx.x;             // 2304 = 384bh * 3ws * 2side
  const int side = bx & 1;
  const int r0 = bx >> 1;
  const int ws = r0 % 3, bh = r0 / 3;
  const int b = bh / 192, h = bh % 192;
  const int w0 = ws * 64;

  const float*    x  = side ? xr  : xl;
  const ushort_t* W  = side ? Wr  : Wl;
  const float*    ab = side ? abr : abl;
  ushort_t* qhT = side ? qhTr : qhTl;
  ushort_t* qwT = side ? qwTr : qwTl;
  ushort_t* V   = side ? Vr   : Vl;

  const int tid = threadIdx.x;
  const int wave = tid >> 6, lane = tid & 63, lr = lane & 15, lg = lane >> 4;

  if (tid < 64) gsum[tid] = 0.f;

  // ---- stage full B: thread (kq=tid>>6, n=tid&63) loads k = s*32 + kq*4 + j ----
  {
    const int kq = wave, n = lane;
    const float* xb = x + (size_t)b*PL + h*192 + w0 + n;
    float gv[24];
    #pragma unroll
    for (int s = 0; s < 6; ++s)
      #pragma unroll
      for (int j = 0; j < 4; ++j)
        gv[s*4 + j] = xb[(size_t)(s*32 + kq*4 + j)*NN];
    float sA = 0.f, sB = 0.f;
    char* Bb = (char*)sm.B;
    const int slot = 16*((kq >> 1) ^ ((n >> 1) & 3)) + 8*(kq & 1);
    #pragma unroll
    for (int s = 0; s < 6; ++s) {
      union { ushort_t us[4]; u32x2 v; } t2;
      #pragma unroll
      for (int j = 0; j < 4; ++j) {
        float g = gv[s*4 + j];
        t2.us[j] = f2bf(g);
        sA += g; sB += g*g;
      }
      *(u32x2*)(Bb + n*384 + s*64 + slot) = t2.v;
    }
    spart[kq][n] = sA; spart2[kq][n] = sB;
  }
  __syncthreads();

  if (tid < 64) {
    float s = 0.f, s2 = 0.f;
    #pragma unroll
    for (int q = 0; q < 8; ++q) { s += spart[q][tid]; s2 += spart2[q][tid]; }
    float mu = s * (1.f/192.f);
    float var = s2 * (1.f/192.f) - mu*mu;
    smu[tid] = mu;
    srs[tid] = rsqrtf(var + 1e-6f);
  }

  // ---- barrier-free K loop: rows 48*wave .. +47, cols 0..63 ----
  const ushort_t* wbase = W + (size_t)(48*wave + lr)*192 + lg*8;
  const char* Bb = (const char*)sm.B;
  const f32x4 fz = {0.f, 0.f, 0.f, 0.f};
  f32x4 acc[3][4];
  #pragma unroll
  for (int mf = 0; mf < 3; ++mf)
    #pragma unroll
    for (int nf = 0; nf < 4; ++nf) acc[mf][nf] = fz;

  #pragma unroll
  for (int ks = 0; ks < 6; ++ks) {
    bf16x8 bfr[4];
    #pragma unroll
    for (int nf = 0; nf < 4; ++nf) {
      int n_ = nf*16 + lr;
      bfr[nf] = lds8((const ushort_t*)(Bb + n_*384 + ks*64 + 16*(lg ^ ((n_ >> 1) & 3))));
    }
    bf16x8 afr[3];
    #pragma unroll
    for (int mf = 0; mf < 3; ++mf)
      afr[mf] = lds8(wbase + (size_t)mf*16*192 + ks*32);
    #pragma unroll
    for (int mf = 0; mf < 3; ++mf)
      #pragma unroll
      for (int nf = 0; nf < 4; ++nf)
        acc[mf][nf] = mfma16(afr[mf], bfr[nf], acc[mf][nf]);
  }
  __syncthreads();                       // B reads done; smu/srs visible

  // ---- LN fixup for q rows (waves 0-3 => rows < 192) ----
  if (wave < 4) {
    float rst[4], mrs[4];
    #pragma unroll
    for (int nf = 0; nf < 4; ++nf) {
      int n_ = nf*16 + lr;
      float rs = srs[n_];
      rst[nf] = rs;
      mrs[nf] = smu[n_] * rs;
    }
    #pragma unroll
    for (int mf = 0; mf < 3; ++mf) {
      int m = 48*wave + 16*mf + 4*lg;
      #pragma unroll
      for (int i = 0; i < 4; ++i) {
        float a_ = ab[m + i], bb = ab[192 + m + i];
        #pragma unroll
        for (int nf = 0; nf < 4; ++nf)
          acc[mf][nf][i] = acc[mf][nf][i]*rst[nf] + bb*mrs[nf] + a_;
      }
    }
  }

  char* Tb = (char*)sm.T;
  // ---- phase qh: rows 0..63 -> T[col][c], store qhT [b][w][h][c] ----
  if (wave < 4) {
    #pragma unroll
    for (int mf = 0; mf < 3; ++mf) {
      int base = 48*wave + 16*mf;
      if ((base >> 6) == 0) {
        #pragma unroll
        for (int nf = 0; nf < 4; ++nf) {
          u32x2 v = { cvtpk(acc[mf][nf][0], acc[mf][nf][1]),
                      cvtpk(acc[mf][nf][2], acc[mf][nf][3]) };
          *(u32x2*)(Tb + (nf*16 + lr)*144 + (base + 4*lg)*2) = v;
        }
      }
    }
  }
  __syncthreads();
  {
    int w = tid >> 3, c8 = tid & 7;
    u32x4 v = *(const u32x4*)(Tb + w*144 + c8*16);
    *(u32x4*)&qhT[(((size_t)b*192 + w0 + w)*192 + h)*64 + c8*8] = v;
  }
  __syncthreads();

  // ---- phase qw: rows 64..127 -> T, store qwT [b][h][w][c] ----
  if (wave < 4) {
    #pragma unroll
    for (int mf = 0; mf < 3; ++mf) {
      int base = 48*wave + 16*mf;
      if ((base >> 6) == 1) {
        #pragma unroll
        for (int nf = 0; nf < 4; ++nf) {
          u32x2 v = { cvtpk(acc[mf][nf][0], acc[mf][nf][1]),
                      cvtpk(acc[mf][nf][2], acc[mf][nf][3]) };
          *(u32x2*)(Tb + (nf*16 + lr)*144 + (base - 64 + 4*lg)*2) = v;
        }
      }
    }
  }
  __syncthreads();
  {
    int w = tid >> 3, c8 = tid & 7;
    u32x4 v = *(const u32x4*)(Tb + w*144 + c8*16);
    *(u32x4*)&qwT[(((size_t)b*192 + h)*192 + w0 + w)*64 + c8*8] = v;
  }
  __syncthreads();

  // ---- V chunks (waves 4-7, rows 192..383 => c 0..191) + GAP in ch 0 ----
  #pragma unroll
  for (int ch = 0; ch < 3; ++ch) {
    if (wave >= 4) {
      #pragma unroll
      for (int mf = 0; mf < 3; ++mf) {
        int vc = 48*(wave - 4) + 16*mf;
        if ((vc >> 6) == ch) {
          int cc = vc - 64*ch + 4*lg;
          #pragma unroll
          for (int nf = 0; nf < 4; ++nf)
            #pragma unroll
            for (int i = 0; i < 4; ++i)
              *(ushort_t*)(Tb + (cc + i)*144 + (nf*16 + lr)*2) = f2bf(acc[mf][nf][i]);
        }
      }
    } else if (ch == 0) {
      // GAP: rows 128..191 (grp2): fixed q_c summed over this block's 64 cols
      #pragma unroll
      for (int mf = 0; mf < 3; ++mf) {
        int base = 48*wave + 16*mf;
        if ((base >> 6) == 2) {
          #pragma unroll
          for (int i = 0; i < 4; ++i) {
            float part = acc[mf][0][i] + acc[mf][1][i] + acc[mf][2][i] + acc[mf][3][i];
            #pragma unroll
            for (int off = 1; off < 16; off <<= 1) part += __shfl_xor(part, off);
            if (lr == 0) atomicAdd(&gsum[base - 128 + 4*lg + i], part);
          }
        }
      }
    }
    __syncthreads();
    {
      int cc = tid >> 3, w8 = tid & 7;
      u32x4 v = *(const u32x4*)(Tb + cc*144 + w8*16);
      *(u32x4*)&V[((size_t)b*192 + ch*64 + cc)*NN + h*192 + w0 + w8*8] = v;
    }
    if (ch == 0 && tid < 64)
      gpart[(((size_t)(side*2 + b)*192 + h)*3 + ws)*64 + tid] = gsum[tid];
    __syncthreads();
  }
}

// ---------------- repack v_h (ch 0..63 of V): [b][c][h][w] -> [b][c][w][h] ----------------
__global__ void k_repack_v(const ushort_t* __restrict__ Vl, const ushort_t* __restrict__ Vr,
                           ushort_t* __restrict__ vhTl, ushort_t* __restrict__ vhTr) {
  __shared__ ushort_t Ls[64*72];
  const ushort_t* V = blockIdx.y ? Vr : Vl;
  ushort_t* out = blockIdx.y ? vhTr : vhTl;
  int bx = blockIdx.x;                    // 1152 = 2b * 64c * 9 tiles
  int b = bx / 576, rem = bx % 576;
  int c = rem / 9, tt = rem % 9;
  int h0 = (tt/3)*64, w0 = (tt%3)*64;
  int tid = threadIdx.x;
  #pragma unroll
  for (int i = 0; i < 2; ++i) {
    int idx = tid + 256*i;
    int hh = idx >> 3, wb = idx & 7;
    *(u32x4*)&Ls[hh*72 + wb*8] =
      *(const u32x4*)&V[(size_t)(b*192 + c)*NN + (h0+hh)*192 + w0 + wb*8];
  }
  __syncthreads();
  #pragma unroll
  for (int i = 0; i < 2; ++i) {
    int idx = tid + 256*i;
    int ww = idx >> 3, hb = idx & 7;
    union { ushort_t us[8]; u32x4 v; } tu;
    #pragma unroll
    for (int j = 0; j < 8; ++j) tu.us[j] = Ls[(hb*8+j)*72 + ww];
    *(u32x4*)&out[(size_t)(b*64 + c)*NN + (w0+ww)*192 + h0 + hb*8] = tu.v;
  }
}

// ------- fused axial attention; O written [b][s0][col][c64] via LDS transpose -------
__global__ __launch_bounds__(256, 2) void k_attn(
    const ushort_t* __restrict__ qhTl, const ushort_t* __restrict__ qhTr,
    const ushort_t* __restrict__ qwTl, const ushort_t* __restrict__ qwTr,
    const ushort_t* __restrict__ Vl,  const ushort_t* __restrict__ Vr,
    const ushort_t* __restrict__ vhTl, const ushort_t* __restrict__ vhTr,
    const float* __restrict__ sch, const float* __restrict__ scw,
    ushort_t* __restrict__ Oh1, ushort_t* __restrict__ Oh2,
    ushort_t* __restrict__ Ow1, ushort_t* __restrict__ Ow2) {
  __shared__ ushort_t Qsl[192*64];   // swizzled [row][slot^row&7]; reused as O-transpose buf
  __shared__ ushort_t Qsr[192*64];
  __shared__ ushort_t Vs[64*192];    // swizzled [c][slot^c&7]
  __shared__ float md[192*2];        // per-col (max, 1/den) from pass1

  const int tid = threadIdx.x;
  const int wave = tid >> 6, lane = tid & 63, lr = lane & 15, lg = lane >> 4;
  const int bx = blockIdx.x;
  const int mode = bx / 384;
  const int b = (bx % 384) / 192, s0 = bx % 192;
  const float scl = (mode ? scw : sch)[0];

  const ushort_t* ql = (mode ? qwTl : qhTl) + (size_t)(b*192 + s0)*12288;
  const ushort_t* qr = (mode ? qwTr : qhTr) + (size_t)(b*192 + s0)*12288;
  const ushort_t* vr = mode ? Vr + (size_t)(b*192 + 64)*NN + s0*192
                            : vhTr + (size_t)b*PL64 + s0*192;
  const ushort_t* vl = mode ? Vl + (size_t)(b*192 + 64)*NN + s0*192
                            : vhTl + (size_t)b*PL64 + s0*192;
  ushort_t* og1 = (mode ? Ow1 : Oh1) + (size_t)(b*192 + s0)*12288;
  ushort_t* og2 = (mode ? Ow2 : Oh2) + (size_t)(b*192 + s0)*12288;

  // ---- stage Q_l, Q_r, V_r (swizzled) ----
  #pragma unroll
  for (int i = 0; i < 6; ++i) {
    int idx = tid + 256*i;
    int r = idx >> 3, sl = idx & 7;
    int dq = r*64 + ((sl ^ (r & 7)) << 3);
    *(u32x4*)&Qsl[dq] = *(const u32x4*)&ql[idx*8];
    *(u32x4*)&Qsr[dq] = *(const u32x4*)&qr[idx*8];
    int c = idx / 24, gs = idx % 24;
    *(u32x4*)&Vs[c*192 + ((gs ^ (c & 7)) << 3)] = *(const u32x4*)&vr[(size_t)c*NN + gs*8];
  }
  __syncthreads();

  const f32x4 fz = {0.f, 0.f, 0.f, 0.f};
  f32x4 acc[12][3];
  unsigned pk[3][12][2];

  auto qk = [&](bool swap) {
    const ushort_t* A  = swap ? Qsl : Qsr;
    const ushort_t* Bq = swap ? Qsr : Qsl;
    #pragma unroll
    for (int mf = 0; mf < 12; ++mf)
      #pragma unroll
      for (int nf = 0; nf < 3; ++nf) acc[mf][nf] = fz;
    __builtin_amdgcn_s_setprio(1);
    #pragma unroll
    for (int kh = 0; kh < 2; ++kh) {
      bf16x8 bq[3];
      #pragma unroll
      for (int nf = 0; nf < 3; ++nf) {
        int r = wave*48 + nf*16 + lr;
        bq[nf] = lds8(&Bq[r*64 + (((kh*4 + lg) ^ (r & 7)) << 3)]);
      }
      #pragma unroll
      for (int mf = 0; mf < 12; ++mf) {
        int r = mf*16 + lr;
        bf16x8 aq = lds8(&A[r*64 + (((kh*4 + lg) ^ (r & 7)) << 3)]);
        #pragma unroll
        for (int nf = 0; nf < 3; ++nf) acc[mf][nf] = mfma16(aq, bq[nf], acc[mf][nf]);
      }
    }
    __builtin_amdgcn_s_setprio(0);
  };

  auto smpack = [&](bool store_md) {
    #pragma unroll
    for (int nf = 0; nf < 3; ++nf) {
      float mx = -3.4e38f;
      #pragma unroll
      for (int mf = 0; mf < 12; ++mf)
        #pragma unroll
        for (int i = 0; i < 4; ++i) {
          float v = acc[mf][nf][i] * scl;
          acc[mf][nf][i] = v;
          mx = fmaxf(mx, v);
        }
      mx = fmaxf(mx, __shfl_xor(mx, 16));
      mx = fmaxf(mx, __shfl_xor(mx, 32));
      float den = 0.f;
      #pragma unroll
      for (int mf = 0; mf < 12; ++mf)
        #pragma unroll
        for (int i = 0; i < 4; ++i) {
          float e = __expf(acc[mf][nf][i] - mx);
          acc[mf][nf][i] = e;
          den += e;
        }
      den += __shfl_xor(den, 16);
      den += __shfl_xor(den, 32);
      float rd = 1.f / den;
      if (store_md && lg == 0) {
        int col = wave*48 + nf*16 + lr;
        md[col*2] = mx; md[col*2+1] = rd;
      }
      #pragma unroll
      for (int mf = 0; mf < 12; ++mf) {
        pk[nf][mf][0] = cvtpk(acc[mf][nf][0]*rd, acc[mf][nf][1]*rd);
        pk[nf][mf][1] = cvtpk(acc[mf][nf][2]*rd, acc[mf][nf][3]*rd);
      }
    }
  };

  // PV -> bf16 fragment pairs (obf[mf][nf] = packed c=(mf*16+lg*4)+0..3 at col)
  auto pv = [&](unsigned obf[4][3][2]) {
    f32x4 o[4][3];
    #pragma unroll
    for (int mf = 0; mf < 4; ++mf)
      #pragma unroll
      for (int nf = 0; nf < 3; ++nf) o[mf][nf] = fz;
    const int sA = lr + 32*(lg & 1), sB = sA + 16;
    const bool hi = (lg >> 1) != 0;
    __builtin_amdgcn_s_setprio(1);
    #pragma unroll
    for (int ks = 0; ks < 6; ++ks) {
      bf16x8 av[4];
      #pragma unroll
      for (int mf = 0; mf < 4; ++mf) {
        int c = mf*16 + lr;
        av[mf] = lds8(&Vs[c*192 + (((4*ks + lg) ^ (c & 7)) << 3)]);
      }
      #pragma unroll
      for (int nf = 0; nf < 3; ++nf) {
        unsigned w0a = (unsigned)__shfl((int)pk[nf][2*ks  ][0], sA);
        unsigned w0b = (unsigned)__shfl((int)pk[nf][2*ks+1][0], sA);
        unsigned w1a = (unsigned)__shfl((int)pk[nf][2*ks  ][1], sA);
        unsigned w1b = (unsigned)__shfl((int)pk[nf][2*ks+1][1], sA);
        unsigned w2a = (unsigned)__shfl((int)pk[nf][2*ks  ][0], sB);
        unsigned w2b = (unsigned)__shfl((int)pk[nf][2*ks+1][0], sB);
        unsigned w3a = (unsigned)__shfl((int)pk[nf][2*ks  ][1], sB);
        unsigned w3b = (unsigned)__shfl((int)pk[nf][2*ks+1][1], sB);
        u32x4 wv = { hi ? w0b : w0a, hi ? w1b : w1a, hi ? w2b : w2a, hi ? w3b : w3a };
        bf16x8 bp = __builtin_bit_cast(bf16x8, wv);
        #pragma unroll
        for (int mf = 0; mf < 4; ++mf) o[mf][nf] = mfma16(av[mf], bp, o[mf][nf]);
      }
    }
    __builtin_amdgcn_s_setprio(0);
    #pragma unroll
    for (int mf = 0; mf < 4; ++mf)
      #pragma unroll
      for (int nf = 0; nf < 3; ++nf) {
        obf[mf][nf][0] = cvtpk(o[mf][nf][0], o[mf][nf][1]);
        obf[mf][nf][1] = cvtpk(o[mf][nf][2], o[mf][nf][3]);
      }
  };

  // write packed O frags into Qsl region as [col(192)][c(64)] with XOR swizzle
  auto owrite = [&](unsigned obf[4][3][2]) {
    char* Ot = (char*)Qsl;
    #pragma unroll
    for (int mf = 0; mf < 4; ++mf)
      #pragma unroll
      for (int nf = 0; nf < 3; ++nf) {
        int col = wave*48 + nf*16 + lr;
        int byte = col*128 + ((mf*32 + lg*8) ^ ((col & 7) << 4));
        u32x2 v = { obf[mf][nf][0], obf[mf][nf][1] };
        *(u32x2*)(Ot + byte) = v;
      }
  };

  // coalesced store: [s0][col][c] contiguous 24KB slab
  auto ostore = [&](ushort_t* og) {
    const char* Ot = (const char*)Qsl;
    #pragma unroll
    for (int it = 0; it < 6; ++it) {
      int id = tid + 256*it;
      int col = id >> 3, s = id & 7;
      int byte = col*128 + ((s*16) ^ ((col & 7) << 4));
      u32x4 v = *(const u32x4*)(Ot + byte);
      *(u32x4*)&og[(size_t)col*64 + s*8] = v;
    }
  };

  // ---- pass 1 ----
  qk(false);
  smpack(true);
  unsigned o1bf[4][3][2];
  pv(o1bf);

  u32x4 vlr[6];                           // prefetch V_l (T14)
  #pragma unroll
  for (int i = 0; i < 6; ++i) {
    int idx = tid + 256*i;
    int c = idx / 24, gs = idx % 24;
    vlr[i] = *(const u32x4*)&vl[(size_t)c*NN + gs*8];
  }

  // ---- pass 2 QK (Q still resident) ----
  qk(true);
  __syncthreads();                        // all Q/Vs reads + md writes done

  owrite(o1bf);                           // O1 -> Qsl region
  #pragma unroll
  for (int i = 0; i < 6; ++i) {           // V_l -> Vs
    int idx = tid + 256*i;
    int c = idx / 24, gs = idx % 24;
    *(u32x4*)&Vs[c*192 + ((gs ^ (c & 7)) << 3)] = vlr[i];
  }

  if (mode == 0) {                        // H: reuse pass1 stats keyed by row h
    #pragma unroll
    for (int mf = 0; mf < 12; ++mf)
      #pragma unroll
      for (int i = 0; i < 4; ++i) {
        int row = mf*16 + lg*4 + i;
        float m_ = md[row*2], rd_ = md[row*2+1];
        #pragma unroll
        for (int nf = 0; nf < 3; ++nf)
          acc[mf][nf][i] = __expf(acc[mf][nf][i]*scl - m_) * rd_;
      }
    #pragma unroll
    for (int nf = 0; nf < 3; ++nf)
      #pragma unroll
      for (int mf = 0; mf < 12; ++mf) {
        pk[nf][mf][0] = cvtpk(acc[mf][nf][0], acc[mf][nf][1]);
        pk[nf][mf][1] = cvtpk(acc[mf][nf][2], acc[mf][nf][3]);
      }
  } else {
    smpack(false);
  }
  __syncthreads();                        // O1 LDS + V_l staged

  ostore(og1);
  unsigned o2bf[4][3][2];
  pv(o2bf);
  __syncthreads();                        // O1 LDS reads done
  owrite(o2bf);
  __syncthreads();
  ostore(og2);
}

// ---------------- SE: reduce gpart + MLP ----------------
__global__ void k_se(const float* __restrict__ gpart, const float* __restrict__ w1,
                     const float* __restrict__ w2, float* __restrict__ sea) {
  __shared__ float psum[256];
  __shared__ float p[2][64];
  __shared__ float h1[2][8];
  __shared__ float lgt[2][128];
  __shared__ float mred[2], dred[2];
  int t = threadIdx.x;
  {
    int b = t >> 7, sideh = (t >> 6) & 1, c = t & 63;
    float s = 0.f;
    for (int j = 0; j < 576; ++j)
      s += gpart[((size_t)(sideh*2 + b)*576 + j)*64 + c];
    psum[t] = s;
  }
  __syncthreads();
  if (t < 128) {
    int b = t >> 6, c = t & 63;
    p[b][c] = (psum[b*128 + c] + psum[b*128 + 64 + c]) * (1.f/36864.f);
  }
  __syncthreads();
  if (t < 16) {
    int bb = t >> 3, j = t & 7;
    float s = 0.f;
    for (int k = 0; k < 64; ++k) s += p[bb][k] * w1[j*64 + k];
    h1[bb][j] = fmaxf(s, 0.f);
  }
  __syncthreads();
  {
    int bb = t >> 7, o = t & 127;
    float s = 0.f;
    #pragma unroll
    for (int j = 0; j < 8; ++j) s += h1[bb][j] * w2[o*8 + j];
    lgt[bb][o] = s;
  }
  __syncthreads();
  if (t < 2) {
    float mx = -3.4e38f;
    for (int o = 0; o < 128; ++o) mx = fmaxf(mx, lgt[t][o]);
    float d = 0.f;
    for (int o = 0; o < 128; ++o) d += __expf(lgt[t][o] - mx);
    mred[t] = mx; dred[t] = d;
  }
  __syncthreads();
  {
    int bb = t >> 7, o = t & 127;
    sea[bb*128 + o] = __expf(lgt[bb][o] - mred[bb]) / dred[bb];
  }
}

// --------- unified epilogue: block (dir,b,h); O layouts [sp1][sp2][c] ---------
__global__ __launch_bounds__(256, 4) void k_ep(
    const ushort_t* __restrict__ Oh1, const ushort_t* __restrict__ Oh2,
    const ushort_t* __restrict__ Ow1, const ushort_t* __restrict__ Ow2,
    const ushort_t* __restrict__ Vl, const ushort_t* __restrict__ Vr,
    const float* __restrict__ sea,
    const float* __restrict__ xl, const float* __restrict__ xr,
    const float* __restrict__ ls1, const float* __restrict__ ls2,
    float* __restrict__ out) {
  __shared__ ushort_t T[192*64];          // 24KB swizzled [w][c]
  const int gid = blockIdx.x;             // 768 = 2dir*2b*192h
  const int h = gid % 192;
  const int b = (gid / 192) % 2;
  const int dir = gid / 384;
  const int tid = threadIdx.x;
  const float* xin = dir ? xr : xl;
  const float* ls  = dir ? ls2 : ls1;
  const ushort_t* Oh = dir ? Oh2 : Oh1;
  const ushort_t* Ow = dir ? Ow2 : Ow1;
  const ushort_t* Vv = dir ? Vr  : Vl;
  float* outp = out + (size_t)dir*TOT;

  const int c0 = (tid / 24) * 8, wseg = tid % 24, w0 = wseg * 8;
  const int Srd = (wseg & 7) << 4;

  // transpose T -> out channels [cbase + c0 .. +7]
  auto flush = [&](int cbase) {
    if (tid < 192) {
      u32x4 r[8];
      #pragma unroll
      for (int j = 0; j < 8; ++j)
        r[j] = *(const u32x4*)((const char*)T + (w0 + j)*128 + ((c0*2) ^ Srd));
      #pragma unroll
      for (int k = 0; k < 8; ++k) {
        int c = cbase + c0 + k;
        float lsv = ls[c];
        size_t oo = (size_t)(b*192 + c)*NN + h*192 + w0;
        f32x4 xa = *(const f32x4*)&xin[oo];
        f32x4 xb2 = *(const f32x4*)&xin[oo + 4];
        f32x4 r0, r1;
        #pragma unroll
        for (int j = 0; j < 4; ++j) r0[j] = bf2f(((const ushort_t*)&r[j])[k])*lsv + xa[j];
        #pragma unroll
        for (int j = 0; j < 4; ++j) r1[j] = bf2f(((const ushort_t*)&r[4+j])[k])*lsv + xb2[j];
        *(f32x4*)&outp[oo] = r0;
        *(f32x4*)&outp[oo + 4] = r1;
      }
    }
  };

  // Phase A: c 0..63 from Oh[b][w][h][c]
  {
    const ushort_t* ohb = Oh + ((size_t)b*192*192 + h)*64;
    #pragma unroll
    for (int it = 0; it < 6; ++it) {
      int id = tid + 256*it;
      int w = id >> 3, s = id & 7;
      u32x4 v = *(const u32x4*)&ohb[(size_t)w*12288 + s*8];
      *(u32x4*)((char*)T + w*128 + ((s*16) ^ (((w >> 3) & 7) << 4))) = v;
    }
  }
  __syncthreads();
  flush(0);
  __syncthreads();

  // Phase B: c 64..127 from Ow[b][h][w][c] (contiguous slab)
  {
    const ushort_t* owb = Ow + ((size_t)b*192 + h)*12288;
    #pragma unroll
    for (int it = 0; it < 6; ++it) {
      int id = tid + 256*it;
      int w = id >> 3, s = id & 7;
      u32x4 v = *(const u32x4*)&owb[id*8];
      *(u32x4*)((char*)T + w*128 + ((s*16) ^ (((w >> 3) & 7) << 4))) = v;
    }
  }
  __syncthreads();
  flush(64);

  // Phase C: c 128..191 elementwise SE from V
  #pragma unroll
  for (int it = 0; it < 6; ++it) {
    int id = tid + 256*it;
    int cc = id / 24, ws = (id % 24) * 8;
    float lsv = ls[128 + cc] * sea[b*128 + dir*64 + cc];
    size_t oo = (size_t)(b*192 + 128 + cc)*NN + h*192 + ws;
    u32x4 sv = *(const u32x4*)&Vv[(size_t)(b*192 + 128 + cc)*NN + h*192 + ws];
    const ushort_t* sp = (const ushort_t*)&sv;
    f32x4 xa = *(const f32x4*)&xin[oo];
    f32x4 xb2 = *(const f32x4*)&xin[oo + 4];
    f32x4 r0, r1;
    #pragma unroll
    for (int j = 0; j < 4; ++j) r0[j] = bf2f(sp[j])*lsv + xa[j];
    #pragma unroll
    for (int j = 0; j < 4; ++j) r1[j] = bf2f(sp[4+j])*lsv + xb2[j];
    *(f32x4*)&outp[oo] = r0;
    *(f32x4*)&outp[oo + 4] = r1;
  }
}

extern "C" void kernel_launch(void* const* d_in, const int* in_sizes, int n_in,
                              void* d_out, int out_size, void* d_ws, size_t ws_size,
                              hipStream_t stream) {
  const float* x_l  = (const float*)d_in[0];
  const float* x_r  = (const float*)d_in[1];
  const float* lnlw = (const float*)d_in[2];
  const float* lnlb = (const float*)d_in[3];
  const float* lnrw = (const float*)d_in[4];
  const float* lnrb = (const float*)d_in[5];
  const float* wq_l = (const float*)d_in[6];
  const float* wq_r = (const float*)d_in[7];
  const float* wv_l = (const float*)d_in[8];
  const float* wv_r = (const float*)d_in[9];
  const float* w1   = (const float*)d_in[10];
  const float* w2   = (const float*)d_in[11];
  const float* sch  = (const float*)d_in[12];
  const float* scw  = (const float*)d_in[13];
  const float* ls1  = (const float*)d_in[14];
  const float* ls2  = (const float*)d_in[15];
  float* out = (float*)d_out;

  char* ws = (char*)d_ws;
  size_t off = 0;
  auto alloc = [&](size_t bytes) {
    char* p = ws + off;
    off += (bytes + 255) & ~(size_t)255;
    return p;
  };
  ushort_t* Vl   = (ushort_t*)alloc((size_t)2*192*NN*2);
  ushort_t* Vr   = (ushort_t*)alloc((size_t)2*192*NN*2);
  ushort_t* qhTl = (ushort_t*)alloc((size_t)2*64*NN*2);
  ushort_t* qhTr = (ushort_t*)alloc((size_t)2*64*NN*2);
  ushort_t* qwTl = (ushort_t*)alloc((size_t)2*64*NN*2);
  ushort_t* qwTr = (ushort_t*)alloc((size_t)2*64*NN*2);
  ushort_t* vhTl = (ushort_t*)alloc((size_t)2*64*NN*2);
  ushort_t* vhTr = (ushort_t*)alloc((size_t)2*64*NN*2);
  ushort_t* Oh1  = (ushort_t*)alloc((size_t)2*64*NN*2);
  ushort_t* Oh2  = (ushort_t*)alloc((size_t)2*64*NN*2);
  ushort_t* Ow1  = (ushort_t*)alloc((size_t)2*64*NN*2);
  ushort_t* Ow2  = (ushort_t*)alloc((size_t)2*64*NN*2);
  ushort_t* Wl   = (ushort_t*)alloc((size_t)384*192*2);
  ushort_t* Wr   = (ushort_t*)alloc((size_t)384*192*2);
  float* abl = (float*)alloc(384*4);
  float* abr = (float*)alloc(384*4);
  float* gpart = (float*)alloc((size_t)2*2*576*64*4);
  float* sea = (float*)alloc(2*128*4);
  (void)in_sizes; (void)n_in; (void)out_size; (void)ws_size;

  k_prep<<<384, 192, 0, stream>>>(wq_l, wv_l, lnlw, lnlb, Wl, abl);
  k_prep<<<384, 192, 0, stream>>>(wq_r, wv_r, lnrw, lnrb, Wr, abr);
  k_proj<<<2304, 512, 0, stream>>>(x_l, x_r, Wl, Wr, abl, abr,
                                   qhTl, qhTr, qwTl, qwTr, Vl, Vr, gpart);
  k_repack_v<<<dim3(1152, 2), 256, 0, stream>>>(Vl, Vr, vhTl, vhTr);
  k_attn<<<768, 256, 0, stream>>>(qhTl, qhTr, qwTl, qwTr, Vl, Vr, vhTl, vhTr,
                                  sch, scw, Oh1, Oh2, Ow1, Ow2);
  k_se<<<1, 256, 0, stream>>>(gpart, w1, w2, sea);
  k_ep<<<768, 256, 0, stream>>>(Oh1, Oh2, Ow1, Ow2, Vl, Vr, sea,
                                x_l, x_r, ls1, ls2, out);
}